// Round 8
// baseline (358.093 us; speedup 1.0000x reference)
//
#include <hip/hip_runtime.h>
#include <hip/hip_bf16.h>
#include <stdint.h>

using bf16 = __hip_bfloat16;
typedef __attribute__((ext_vector_type(8))) short short8;
typedef __attribute__((ext_vector_type(4))) float f32x4;

__device__ __forceinline__ short f2bs(float x) {
    union { bf16 h; short s; } u;
    u.h = __float2bfloat16(x);
    return u.s;
}

// ---- fp32 -> bf16 64x64 tile transpose (+ optional row-major bf16 copy) ----
__global__ __launch_bounds__(256)
void transpose_cvt(const float* __restrict__ src, ushort* __restrict__ dstT,
                   ushort* __restrict__ dstN,
                   int R, int C, long sstride, long dstrideT, long dstrideN)
{
    __shared__ __align__(16) ushort t[64][72];
    const float* s = src + (size_t)blockIdx.z * sstride;
    ushort*      dT = dstT + (size_t)blockIdx.z * dstrideT;
    const int r0 = blockIdx.y * 64, c0 = blockIdx.x * 64;
    const int tid = threadIdx.x;
#pragma unroll
    for (int ii = 0; ii < 4; ++ii) {
        int idx = ii * 256 + tid;
        int r = idx >> 4, c4 = (idx & 15) * 4;
        float4 v = *(const float4*)&s[(size_t)(r0 + r) * C + c0 + c4];
        union { ushort u[4]; uint2 q; } o;
        o.u[0] = (ushort)f2bs(v.x); o.u[1] = (ushort)f2bs(v.y);
        o.u[2] = (ushort)f2bs(v.z); o.u[3] = (ushort)f2bs(v.w);
        *(uint2*)&t[r][c4] = o.q;
        if (dstN) {
            ushort* dN = dstN + (size_t)blockIdx.z * dstrideN;
            *(uint2*)&dN[(size_t)(r0 + r) * C + c0 + c4] = o.q;
        }
    }
    __syncthreads();
#pragma unroll
    for (int ii = 0; ii < 2; ++ii) {
        int idx = ii * 256 + tid;
        int c = idx >> 3, r8 = (idx & 7) * 8;
        union { ushort u[8]; uint4 v; } tmp;
#pragma unroll
        for (int j = 0; j < 8; ++j) tmp.u[j] = t[r8 + j][c];
        *(uint4*)&dT[(size_t)(c0 + c) * R + r0 + r8] = tmp.v;
    }
}

// -------- C = A * B^T, no-LDS wave-level GEMM (round-7 restructure) --------
// Block = 64 threads = 1 wave; wave computes (MFRAG*16) x (NFRAG*16).
// Fragments loaded straight from global (K-contiguous 16B per lane) — no
// LDS, no __syncthreads, so loads pipeline across K-iters with vmcnt(N).
// MODE 0: bf16 store. MODE 1: fp32 atomicAdd (split-K). MODE 2: fp32 store.
// A_F32: A operand fp32 in global (32B/lane load + cvt).
template <int MODE, int A_F32, int MFRAG, int NFRAG>
__global__ __launch_bounds__(64, 4)
void gemm_wv(const void* __restrict__ Av, const bf16* __restrict__ B,
             void* __restrict__ Cv, int M, int N, int K, int kChunks,
             long sA, long sB, long sC)
{
    const int z     = blockIdx.z;
    const int batch = z / kChunks;
    const int chunk = z - batch * kChunks;
    const int kLen  = K / kChunks;
    const int k0    = chunk * kLen;
    const int m0    = blockIdx.y * (MFRAG * 16);
    const int n0    = blockIdx.x * (NFRAG * 16);
    const int lane  = threadIdx.x;
    const int ml    = lane & 15;
    const int q     = lane >> 4;

    const bf16* Bb = B + (size_t)batch * sB;
    const bf16* bp[NFRAG];
#pragma unroll
    for (int f = 0; f < NFRAG; ++f)
        bp[f] = Bb + (size_t)(n0 + f * 16 + ml) * K + k0 + q * 8;

    const float* af32[MFRAG];
    const bf16*  af16[MFRAG];
    if constexpr (A_F32) {
        const float* Ab = (const float*)Av + (size_t)batch * sA;
#pragma unroll
        for (int f = 0; f < MFRAG; ++f)
            af32[f] = Ab + (size_t)(m0 + f * 16 + ml) * K + k0 + q * 8;
    } else {
        const bf16* Ab = (const bf16*)Av + (size_t)batch * sA;
#pragma unroll
        for (int f = 0; f < MFRAG; ++f)
            af16[f] = Ab + (size_t)(m0 + f * 16 + ml) * K + k0 + q * 8;
    }

    f32x4 acc[MFRAG][NFRAG] = {};

    const int nk = kLen / 32;
#pragma unroll 4
    for (int kt = 0; kt < nk; ++kt) {
        short8 af[MFRAG], bfr[NFRAG];
#pragma unroll
        for (int f = 0; f < NFRAG; ++f) {
            bfr[f] = *(const short8*)bp[f];
            bp[f] += 32;
        }
#pragma unroll
        for (int f = 0; f < MFRAG; ++f) {
            if constexpr (A_F32) {
                float4 x0 = *(const float4*)af32[f];
                float4 x1 = *(const float4*)(af32[f] + 4);
                af32[f] += 32;
                af[f][0] = f2bs(x0.x); af[f][1] = f2bs(x0.y);
                af[f][2] = f2bs(x0.z); af[f][3] = f2bs(x0.w);
                af[f][4] = f2bs(x1.x); af[f][5] = f2bs(x1.y);
                af[f][6] = f2bs(x1.z); af[f][7] = f2bs(x1.w);
            } else {
                af[f] = *(const short8*)af16[f];
                af16[f] += 32;
            }
        }
#pragma unroll
        for (int mi = 0; mi < MFRAG; ++mi)
#pragma unroll
            for (int nj = 0; nj < NFRAG; ++nj)
                acc[mi][nj] = __builtin_amdgcn_mfma_f32_16x16x32_bf16(
                    af[mi], bfr[nj], acc[mi][nj], 0, 0, 0);
    }

    // epilogue: C/D layout col=lane&15, row=(lane>>4)*4+r (m89-verified)
#pragma unroll
    for (int mi = 0; mi < MFRAG; ++mi)
#pragma unroll
        for (int nj = 0; nj < NFRAG; ++nj)
#pragma unroll
            for (int r = 0; r < 4; ++r) {
                int row = m0 + mi * 16 + q * 4 + r;
                int col = n0 + nj * 16 + ml;
                if constexpr (MODE == 1) {
                    float* Cf = (float*)Cv + (size_t)batch * sC;
                    atomicAdd(&Cf[(size_t)row * N + col], acc[mi][nj][r]);
                } else if constexpr (MODE == 0) {
                    ushort* Cb = (ushort*)Cv + (size_t)batch * sC;
                    Cb[(size_t)row * N + col] = (ushort)f2bs(acc[mi][nj][r]);
                } else {
                    float* Cf = (float*)Cv + (size_t)batch * sC;
                    Cf[(size_t)row * N + col] = acc[mi][nj][r];
                }
            }
}

// ---------------------------------------------------------------
// fp32 I/O.  O = ((X W^T) X^T) X == X * (W^T (X^T X))   [associative]
//   G  = Xt * Xt^T   (split-K=4, fp32 atomic)     Xt = bf16(X)^T
//   Mt = Gf * Wt^T   (A fp32 on-the-fly cvt; bf16 store)
//   O  = X * Mt^T    (fp32 store; A = Xb bf16 if ws fits, else X fp32)
// d_out scratch (dead before step 7 overwrites):
//   Xt bf16 @0 (16M) | Gf f32 @16M (8M) | Wt @28M (2M)
// ws: [Xb bf16 16M if ws_size>=20M] + Mt bf16 4M.
// ---------------------------------------------------------------
extern "C" void kernel_launch(void* const* d_in, const int* in_sizes, int n_in,
                              void* d_out, int out_size, void* d_ws, size_t ws_size,
                              hipStream_t stream)
{
    const int B = 2, N = 4096, D = 1024;
    const float* X = (const float*)d_in[0];   // [B][N][D] fp32
    const float* W = (const float*)d_in[1];   // [D][D]    fp32
    float* out = (float*)d_out;               // [B][N][D] fp32

    char* ob = (char*)d_out;
    char* ws = (char*)d_ws;
    ushort* Xt = (ushort*)ob;                  // [B][D][N] bf16, 16 MiB
    float*  Gf = (float*)(ob + (16ll << 20));  // [B][D][D] fp32,  8 MiB
    ushort* Wt = (ushort*)(ob + (28ll << 20)); // [D][D]    bf16,  2 MiB

    const bool bigws = ws_size >= (20ull << 20);
    ushort* Xb = bigws ? (ushort*)ws : nullptr;              // [B][N][D] bf16, 16 MiB
    ushort* Mt = (ushort*)(ws + (bigws ? (16ll << 20) : 0)); // [B][D][D] bf16, 4 MiB

    // 1) Xt[b] = bf16(X[b])^T  (+ Xb = bf16(X) row-major when ws allows)
    transpose_cvt<<<dim3(D / 64, N / 64, B), 256, 0, stream>>>(
        X, Xt, Xb, N, D, (long)N * D, (long)D * N, (long)N * D);
    // 2) Wt = bf16(W)^T
    transpose_cvt<<<dim3(D / 64, D / 64, 1), 256, 0, stream>>>(
        W, Wt, nullptr, D, D, 0, 0, 0);
    // 3) zero split-K accumulator
    (void)hipMemsetAsync(Gf, 0, (size_t)B * D * D * sizeof(float), stream);
    // 4) Gf[b] += Xt[b] * Xt[b]^T  (M=N=D, K=4096, split-K 4; 4096 waves)
    gemm_wv<1, 0, 4, 2><<<dim3(D / 32, D / 64, B * 4), 64, 0, stream>>>(
        (const void*)Xt, (const bf16*)Xt, Gf, D, D, N, 4,
        (long)D * N, (long)D * N, (long)D * D);
    // 6) Mt[b] = bf16(Gf[b]) * Wt^T  (M=N=K=D; cvt fused via A_F32)
    gemm_wv<0, 1, 4, 2><<<dim3(D / 32, D / 64, B), 64, 0, stream>>>(
        (const void*)Gf, (const bf16*)Wt, Mt, D, D, D, 1,
        (long)D * D, 0, (long)D * D);
    // 7) O[b] = X[b] * Mt[b]^T  (M=4096, N=D, K=D; 4096 waves)
    if (bigws) {
        gemm_wv<2, 0, 4, 2><<<dim3(D / 32, N / 64, B), 64, 0, stream>>>(
            (const void*)Xb, (const bf16*)Mt, out, N, D, D, 1,
            (long)N * D, (long)D * D, (long)N * D);
    } else {
        gemm_wv<2, 1, 4, 2><<<dim3(D / 32, N / 64, B), 64, 0, stream>>>(
            (const void*)X, (const bf16*)Mt, out, N, D, D, 1,
            (long)N * D, (long)D * D, (long)N * D);
    }
}

// Round 10
// 235.619 us; speedup vs baseline: 1.5198x; 1.5198x over previous
//
#include <hip/hip_runtime.h>
#include <hip/hip_bf16.h>
#include <stdint.h>

using bf16 = __hip_bfloat16;
typedef __attribute__((ext_vector_type(8))) short short8;
typedef __attribute__((ext_vector_type(4))) float f32x4;

#define BM 128
#define BK 32

__device__ __forceinline__ void g2lds16(const void* g, void* l) {
    __builtin_amdgcn_global_load_lds(
        (const __attribute__((address_space(1))) void*)g,
        (__attribute__((address_space(3))) void*)l,
        16, 0, 0);
}

__device__ __forceinline__ short f2bs(float x) {
    union { bf16 h; short s; } u;
    u.h = __float2bfloat16(x);
    return u.s;
}

// ---- LDS XOR swizzles (round-4 fix, used by the LDS gemm) ----
__device__ __forceinline__ int bswz(int row, int cg) { return cg ^ ((row >> 1) & 3); }
__device__ __forceinline__ int fswz(int row, int cg) { return cg ^ (row & 7); }

// Packed MFMA-fragment layout (round-8 fix for transaction-bound loads):
//   elem (row, k) -> [((row>>4)*(K>>5) + (k>>5))*64 + lane]*8 + (k&7),
//   lane = (row&15) + 16*((k>>3)&3)
// One fragment = 64 lanes x 16B contiguous = 1KB coalesced load.

// ---- fp32 -> bf16 transpose (+pack) and optional packed row-major copy ----
// packT=1: dstT gets packed layout (rows=C-dim, K=R-dim); else plain [C][R].
__global__ __launch_bounds__(256)
void transpose_cvt(const float* __restrict__ src, ushort* __restrict__ dstT,
                   ushort* __restrict__ dstN,
                   int R, int C, long sstride, long dstrideT, long dstrideN,
                   int packT)
{
    __shared__ __align__(16) ushort t[64][72];
    const float* s = src + (size_t)blockIdx.z * sstride;
    ushort*      dT = dstT + (size_t)blockIdx.z * dstrideT;
    const int r0 = blockIdx.y * 64, c0 = blockIdx.x * 64;
    const int tid = threadIdx.x;
#pragma unroll
    for (int ii = 0; ii < 4; ++ii) {
        int idx = ii * 256 + tid;
        int r = idx >> 4, c4 = (idx & 15) * 4;
        float4 v = *(const float4*)&s[(size_t)(r0 + r) * C + c0 + c4];
        union { ushort u[4]; uint2 q; } o;
        o.u[0] = (ushort)f2bs(v.x); o.u[1] = (ushort)f2bs(v.y);
        o.u[2] = (ushort)f2bs(v.z); o.u[3] = (ushort)f2bs(v.w);
        *(uint2*)&t[r][c4] = o.q;
        if (dstN) {   // packed row-major: row = r0+r (m), k = c0+c4 (8B write)
            ushort* dN = dstN + (size_t)blockIdx.z * dstrideN;
            int m = r0 + r, k = c0 + c4;
            int lane = (m & 15) + 16 * ((k >> 3) & 3);
            size_t pidx = (((size_t)(m >> 4) * (C >> 5) + (k >> 5)) * 64 + lane) * 8 + (k & 7);
            *(uint2*)&dN[pidx] = o.q;
        }
    }
    __syncthreads();
#pragma unroll
    for (int ii = 0; ii < 2; ++ii) {
        int idx = ii * 256 + tid;
        int c = idx >> 3, r8 = (idx & 7) * 8;
        union { ushort u[8]; uint4 v; } tmp;
#pragma unroll
        for (int j = 0; j < 8; ++j) tmp.u[j] = t[r8 + j][c];
        if (packT) {  // transposed elem: row = c0+c (m-dim), k = r0+r8 (8 elems)
            int m = c0 + c, k = r0 + r8;
            int lane = (m & 15) + 16 * ((k >> 3) & 3);
            size_t pidx = (((size_t)(m >> 4) * (R >> 5) + (k >> 5)) * 64 + lane) * 8;
            *(uint4*)&dT[pidx] = tmp.v;
        } else {
            *(uint4*)&dT[(size_t)(c0 + c) * R + r0 + r8] = tmp.v;
        }
    }
}

// -------- LDS-staged C = A * B^T (round-6 kernel; used for step 6) --------
// MODE 0: bf16 store. MODE 1: fp32 atomic. MODE 2: fp32 store.
// MODE 3: bf16 store in packed-fragment layout (for Mt -> step-7 B operand).
template <int MODE, int A_F32, int NFRAG>
__global__ __launch_bounds__(256)
void gemm_bt(const void* __restrict__ Av, const bf16* __restrict__ B,
             void* __restrict__ Cv, int M, int N, int K, int kChunks,
             long sA, long sB, long sC)
{
    constexpr int BN  = 32 * NFRAG;
    constexpr int BSH = BN / 64;
    __shared__ __align__(16) bf16 lA[BM * BK * (A_F32 ? 2 : 1)];
    __shared__ __align__(16) bf16 lB[BN * BK];

    const int z     = blockIdx.z;
    const int batch = z / kChunks;
    const int chunk = z - batch * kChunks;
    const int kLen  = K / kChunks;
    const int k0    = chunk * kLen;
    const int m0 = blockIdx.y * BM;
    const int n0 = blockIdx.x * BN;
    const int tid  = threadIdx.x;
    const int lane = tid & 63;
    const int wave = tid >> 6;
    const int wr   = wave >> 1, wc = wave & 1;
    const int ml   = lane & 15;
    const int q    = lane >> 4;

    const bf16* Bb = B + (size_t)batch * sB;
    const bf16* bp[BSH];
#pragma unroll
    for (int s = 0; s < BSH; ++s) {
        int idx = s * 256 + tid;
        int row = idx >> 2, cg = idx & 3;
        bp[s] = Bb + (size_t)(n0 + row) * K + k0 + 8 * bswz(row, cg);
    }

    const float* a32[4];
    const bf16*  a16[2];
    if constexpr (A_F32) {
        const float* Ab = (const float*)Av + (size_t)batch * sA;
#pragma unroll
        for (int s = 0; s < 4; ++s) {
            int idx = s * 256 + tid;
            int row = idx >> 3, cg = idx & 7;
            a32[s] = Ab + (size_t)(m0 + row) * K + k0 + 4 * fswz(row, cg);
        }
    } else {
        const bf16* Ab = (const bf16*)Av + (size_t)batch * sA;
#pragma unroll
        for (int s = 0; s < 2; ++s) {
            int idx = s * 256 + tid;
            int row = idx >> 2, cg = idx & 3;
            a16[s] = Ab + (size_t)(m0 + row) * K + k0 + 8 * bswz(row, cg);
        }
    }

    f32x4 acc[4][NFRAG] = {};
    const int nk = kLen / BK;
    for (int kt = 0; kt < nk; ++kt) {
        if constexpr (A_F32) {
            float* lAf = (float*)lA;
#pragma unroll
            for (int s = 0; s < 4; ++s) { g2lds16(a32[s], &lAf[(s * 256 + tid) * 4]); a32[s] += BK; }
        } else {
#pragma unroll
            for (int s = 0; s < 2; ++s) { g2lds16(a16[s], &lA[(s * 256 + tid) * 8]); a16[s] += BK; }
        }
#pragma unroll
        for (int s = 0; s < BSH; ++s) { g2lds16(bp[s], &lB[(s * 256 + tid) * 8]); bp[s] += BK; }
        __syncthreads();

        short8 af[4], bfr[NFRAG];
#pragma unroll
        for (int i = 0; i < 4; ++i) {
            const int rA = wr * 64 + i * 16 + ml;
            if constexpr (A_F32) {
                const float* lAf = (const float*)lA;
                float4 x0 = *(const float4*)&lAf[rA * 32 + 4 * fswz(rA, 2 * q)];
                float4 x1 = *(const float4*)&lAf[rA * 32 + 4 * fswz(rA, 2 * q + 1)];
                af[i][0] = f2bs(x0.x); af[i][1] = f2bs(x0.y);
                af[i][2] = f2bs(x0.z); af[i][3] = f2bs(x0.w);
                af[i][4] = f2bs(x1.x); af[i][5] = f2bs(x1.y);
                af[i][6] = f2bs(x1.z); af[i][7] = f2bs(x1.w);
            } else {
                af[i] = *(const short8*)&lA[rA * 32 + 8 * bswz(rA, q)];
            }
        }
#pragma unroll
        for (int j = 0; j < NFRAG; ++j) {
            const int rB = wc * (16 * NFRAG) + j * 16 + ml;
            bfr[j] = *(const short8*)&lB[rB * 32 + 8 * bswz(rB, q)];
        }
#pragma unroll
        for (int mi = 0; mi < 4; ++mi)
#pragma unroll
            for (int nj = 0; nj < NFRAG; ++nj)
                acc[mi][nj] = __builtin_amdgcn_mfma_f32_16x16x32_bf16(
                    af[mi], bfr[nj], acc[mi][nj], 0, 0, 0);
        __syncthreads();
    }

#pragma unroll
    for (int mi = 0; mi < 4; ++mi)
#pragma unroll
        for (int nj = 0; nj < NFRAG; ++nj)
#pragma unroll
            for (int r = 0; r < 4; ++r) {
                int row = m0 + wr * 64 + mi * 16 + q * 4 + r;
                int col = n0 + wc * (16 * NFRAG) + nj * 16 + ml;
                if constexpr (MODE == 1) {
                    float* Cf = (float*)Cv + (size_t)batch * sC;
                    atomicAdd(&Cf[(size_t)row * N + col], acc[mi][nj][r]);
                } else if constexpr (MODE == 0) {
                    ushort* Cb = (ushort*)Cv + (size_t)batch * sC;
                    Cb[(size_t)row * N + col] = (ushort)f2bs(acc[mi][nj][r]);
                } else if constexpr (MODE == 3) {
                    ushort* Cb = (ushort*)Cv + (size_t)batch * sC;
                    int plane = (row & 15) + 16 * ((col >> 3) & 3);
                    size_t pidx = (((size_t)(row >> 4) * (N >> 5) + (col >> 5)) * 64 + plane) * 8 + (col & 7);
                    Cb[pidx] = (ushort)f2bs(acc[mi][nj][r]);
                } else {
                    float* Cf = (float*)Cv + (size_t)batch * sC;
                    Cf[(size_t)row * N + col] = acc[mi][nj][r];
                }
            }
}

// ---- barrier-free wave GEMM on PACKED operands (steps 4 & 7) ----
// Block = 1 wave; tile (MFRAG*16) x (NFRAG*16); every fragment load is one
// coalesced 1KB global_load_dwordx4. No LDS, no barrier -> loads pipeline
// across K-iters with fine-grained vmcnt.
// MODE 1: fp32 atomicAdd. MODE 2: fp32 store.
template <int MODE, int MFRAG, int NFRAG>
__global__ __launch_bounds__(64, 2)
void gemm_wp(const ushort* __restrict__ Ap, const ushort* __restrict__ Bp,
             void* __restrict__ Cv, int N, int K, int kChunks,
             long sA, long sB, long sC)
{
    const int z      = blockIdx.z;
    const int batch  = z / kChunks;
    const int chunk  = z - batch * kChunks;
    const int ktiles = K >> 5;
    const int nkt    = ktiles / kChunks;
    const int kt0    = chunk * nkt;
    const int m0     = blockIdx.y * (MFRAG * 16);
    const int n0     = blockIdx.x * (NFRAG * 16);
    const int lane   = threadIdx.x;

    const ushort* Ab = Ap + (size_t)batch * sA;
    const ushort* Bb = Bp + (size_t)batch * sB;
    const ushort* ap[MFRAG];
    const ushort* bp[NFRAG];
#pragma unroll
    for (int f = 0; f < MFRAG; ++f)
        ap[f] = Ab + (((size_t)((m0 >> 4) + f) * ktiles + kt0) * 64 + lane) * 8;
#pragma unroll
    for (int f = 0; f < NFRAG; ++f)
        bp[f] = Bb + (((size_t)((n0 >> 4) + f) * ktiles + kt0) * 64 + lane) * 8;

    f32x4 acc[MFRAG][NFRAG] = {};

#pragma unroll 4
    for (int kt = 0; kt < nkt; ++kt) {
        short8 af[MFRAG], bfr[NFRAG];
#pragma unroll
        for (int f = 0; f < MFRAG; ++f) { af[f]  = *(const short8*)ap[f]; ap[f] += 512; }
#pragma unroll
        for (int f = 0; f < NFRAG; ++f) { bfr[f] = *(const short8*)bp[f]; bp[f] += 512; }
#pragma unroll
        for (int mi = 0; mi < MFRAG; ++mi)
#pragma unroll
            for (int nj = 0; nj < NFRAG; ++nj)
                acc[mi][nj] = __builtin_amdgcn_mfma_f32_16x16x32_bf16(
                    af[mi], bfr[nj], acc[mi][nj], 0, 0, 0);
    }

    const int ml = lane & 15, q = lane >> 4;
#pragma unroll
    for (int mi = 0; mi < MFRAG; ++mi)
#pragma unroll
        for (int nj = 0; nj < NFRAG; ++nj)
#pragma unroll
            for (int r = 0; r < 4; ++r) {
                int row = m0 + mi * 16 + q * 4 + r;
                int col = n0 + nj * 16 + ml;
                if constexpr (MODE == 1) {
                    float* Cf = (float*)Cv + (size_t)batch * sC;
                    atomicAdd(&Cf[(size_t)row * N + col], acc[mi][nj][r]);
                } else {
                    float* Cf = (float*)Cv + (size_t)batch * sC;
                    Cf[(size_t)row * N + col] = acc[mi][nj][r];
                }
            }
}

// ---------------------------------------------------------------
// fp32 I/O.  O = X * (W^T (X^T X))   [associative]
//   G  = Xt * Xt^T   (packed wave-GEMM, split-K=4, fp32 atomic)
//   Mt = Gf * Wt^T   (LDS gemm, A fp32 cvt fused; packed-bf16 store)
//   O  = Xb * Mt^T   (packed wave-GEMM, fp32 store)
// d_out scratch: Xt packed @0 (16M) | Gf f32 @16M (8M) | Wt @28M (2M)
// ws: Xb packed 16M + Mt packed 4M  (requires ws >= 20M; fallback path else)
// ---------------------------------------------------------------
extern "C" void kernel_launch(void* const* d_in, const int* in_sizes, int n_in,
                              void* d_out, int out_size, void* d_ws, size_t ws_size,
                              hipStream_t stream)
{
    const int B = 2, N = 4096, D = 1024;
    const float* X = (const float*)d_in[0];
    const float* W = (const float*)d_in[1];
    float* out = (float*)d_out;

    char* ob = (char*)d_out;
    char* ws = (char*)d_ws;
    ushort* Xt = (ushort*)ob;                  // packed [B] rows=D, K=N, 16 MiB
    float*  Gf = (float*)(ob + (16ll << 20));  // [B][D][D] fp32, 8 MiB
    ushort* Wt = (ushort*)(ob + (28ll << 20)); // [D][D] bf16 normal, 2 MiB

    const bool bigws = ws_size >= (20ull << 20);
    ushort* Xb = bigws ? (ushort*)ws : nullptr;              // packed rows=N, K=D
    ushort* Mt = (ushort*)(ws + (bigws ? (16ll << 20) : 0)); // packed (or normal) 4 MiB

    // 1) Xt = packed(bf16(X)^T); Xb = packed(bf16(X)) when ws allows
    transpose_cvt<<<dim3(D / 64, N / 64, B), 256, 0, stream>>>(
        X, Xt, Xb, N, D, (long)N * D, (long)D * N, (long)N * D, 1);
    // 2) Wt = bf16(W)^T (normal layout, consumed by LDS gemm)
    transpose_cvt<<<dim3(D / 64, D / 64, 1), 256, 0, stream>>>(
        W, Wt, nullptr, D, D, 0, 0, 0, 0);
    // 3) zero split-K accumulator
    (void)hipMemsetAsync(Gf, 0, (size_t)B * D * D * sizeof(float), stream);
    // 4) Gf += Xt * Xt^T  (M=N=D, K=4096, split 4; 2048 waves, packed loads)
    gemm_wp<1, 4, 4><<<dim3(D / 64, D / 64, B * 4), 64, 0, stream>>>(
        Xt, Xt, Gf, D, N, 4, (long)D * N, (long)D * N, (long)D * D);
    // 6) Mt = bf16(Gf) * Wt^T  (LDS gemm, packed store when bigws)
    if (bigws) {
        gemm_bt<3, 1, 2><<<dim3(D / 64, D / BM, B), 256, 0, stream>>>(
            (const void*)Gf, (const bf16*)Wt, Mt, D, D, D, 1,
            (long)D * D, 0, (long)D * D);
        // 7) O = Xb * Mt^T  (M=4096, N=D, K=D; 2048 waves, packed loads)
        gemm_wp<2, 4, 4><<<dim3(D / 64, N / 64, B), 64, 0, stream>>>(
            Xb, Mt, out, D, D, 1, (long)N * D, (long)D * D, (long)N * D);
    } else {
        gemm_bt<0, 1, 2><<<dim3(D / 64, D / BM, B), 256, 0, stream>>>(
            (const void*)Gf, (const bf16*)Wt, Mt, D, D, D, 1,
            (long)D * D, 0, (long)D * D);
        gemm_bt<2, 1, 2><<<dim3(D / 64, N / BM, B), 256, 0, stream>>>(
            (const void*)X, (const bf16*)Mt, out, N, D, D, 1,
            (long)N * D, (long)D * D, (long)N * D);
    }
}

// Round 11
// 200.888 us; speedup vs baseline: 1.7825x; 1.1729x over previous
//
#include <hip/hip_runtime.h>
#include <hip/hip_bf16.h>
#include <stdint.h>

using bf16 = __hip_bfloat16;
typedef __attribute__((ext_vector_type(8))) short short8;
typedef __attribute__((ext_vector_type(4))) float f32x4;

#define BM 128
#define BK 32

__device__ __forceinline__ void g2lds16(const void* g, void* l) {
    __builtin_amdgcn_global_load_lds(
        (const __attribute__((address_space(1))) void*)g,
        (__attribute__((address_space(3))) void*)l,
        16, 0, 0);
}

__device__ __forceinline__ short f2bs(float x) {
    union { bf16 h; short s; } u;
    u.h = __float2bfloat16(x);
    return u.s;
}

// ---- LDS XOR swizzles (round-4 fix, used by the LDS gemm) ----
__device__ __forceinline__ int bswz(int row, int cg) { return cg ^ ((row >> 1) & 3); }
__device__ __forceinline__ int fswz(int row, int cg) { return cg ^ (row & 7); }

// Packed MFMA-fragment layout (round-8 fix for transaction-bound loads):
//   elem (row, k) -> [((row>>4)*(K>>5) + (k>>5))*64 + lane]*8 + (k&7),
//   lane = (row&15) + 16*((k>>3)&3)

// ---- fp32 -> bf16 transpose (+pack) and optional packed row-major copy ----
__global__ __launch_bounds__(256)
void transpose_cvt(const float* __restrict__ src, ushort* __restrict__ dstT,
                   ushort* __restrict__ dstN,
                   int R, int C, long sstride, long dstrideT, long dstrideN,
                   int packT)
{
    __shared__ __align__(16) ushort t[64][72];
    const float* s = src + (size_t)blockIdx.z * sstride;
    ushort*      dT = dstT + (size_t)blockIdx.z * dstrideT;
    const int r0 = blockIdx.y * 64, c0 = blockIdx.x * 64;
    const int tid = threadIdx.x;
#pragma unroll
    for (int ii = 0; ii < 4; ++ii) {
        int idx = ii * 256 + tid;
        int r = idx >> 4, c4 = (idx & 15) * 4;
        float4 v = *(const float4*)&s[(size_t)(r0 + r) * C + c0 + c4];
        union { ushort u[4]; uint2 q; } o;
        o.u[0] = (ushort)f2bs(v.x); o.u[1] = (ushort)f2bs(v.y);
        o.u[2] = (ushort)f2bs(v.z); o.u[3] = (ushort)f2bs(v.w);
        *(uint2*)&t[r][c4] = o.q;
        if (dstN) {   // packed row-major: row = r0+r (m), k = c0+c4
            ushort* dN = dstN + (size_t)blockIdx.z * dstrideN;
            int m = r0 + r, k = c0 + c4;
            int lane = (m & 15) + 16 * ((k >> 3) & 3);
            size_t pidx = (((size_t)(m >> 4) * (C >> 5) + (k >> 5)) * 64 + lane) * 8 + (k & 7);
            *(uint2*)&dN[pidx] = o.q;
        }
    }
    __syncthreads();
#pragma unroll
    for (int ii = 0; ii < 2; ++ii) {
        int idx = ii * 256 + tid;
        int c = idx >> 3, r8 = (idx & 7) * 8;
        union { ushort u[8]; uint4 v; } tmp;
#pragma unroll
        for (int j = 0; j < 8; ++j) tmp.u[j] = t[r8 + j][c];
        if (packT) {  // transposed elem: row = c0+c (m), k = r0+r8
            int m = c0 + c, k = r0 + r8;
            int lane = (m & 15) + 16 * ((k >> 3) & 3);
            size_t pidx = (((size_t)(m >> 4) * (R >> 5) + (k >> 5)) * 64 + lane) * 8;
            *(uint4*)&dT[pidx] = tmp.v;
        } else {
            *(uint4*)&dT[(size_t)(c0 + c) * R + r0 + r8] = tmp.v;
        }
    }
}

// -------- LDS-staged C = A * B^T (round-6 kernel; used for step 6) --------
template <int MODE, int A_F32, int NFRAG>
__global__ __launch_bounds__(256)
void gemm_bt(const void* __restrict__ Av, const bf16* __restrict__ B,
             void* __restrict__ Cv, int M, int N, int K, int kChunks,
             long sA, long sB, long sC)
{
    constexpr int BN  = 32 * NFRAG;
    constexpr int BSH = BN / 64;
    __shared__ __align__(16) bf16 lA[BM * BK * (A_F32 ? 2 : 1)];
    __shared__ __align__(16) bf16 lB[BN * BK];

    const int z     = blockIdx.z;
    const int batch = z / kChunks;
    const int chunk = z - batch * kChunks;
    const int kLen  = K / kChunks;
    const int k0    = chunk * kLen;
    const int m0 = blockIdx.y * BM;
    const int n0 = blockIdx.x * BN;
    const int tid  = threadIdx.x;
    const int lane = tid & 63;
    const int wave = tid >> 6;
    const int wr   = wave >> 1, wc = wave & 1;
    const int ml   = lane & 15;
    const int q    = lane >> 4;

    const bf16* Bb = B + (size_t)batch * sB;
    const bf16* bp[BSH];
#pragma unroll
    for (int s = 0; s < BSH; ++s) {
        int idx = s * 256 + tid;
        int row = idx >> 2, cg = idx & 3;
        bp[s] = Bb + (size_t)(n0 + row) * K + k0 + 8 * bswz(row, cg);
    }

    const float* a32[4];
    const bf16*  a16[2];
    if constexpr (A_F32) {
        const float* Ab = (const float*)Av + (size_t)batch * sA;
#pragma unroll
        for (int s = 0; s < 4; ++s) {
            int idx = s * 256 + tid;
            int row = idx >> 3, cg = idx & 7;
            a32[s] = Ab + (size_t)(m0 + row) * K + k0 + 4 * fswz(row, cg);
        }
    } else {
        const bf16* Ab = (const bf16*)Av + (size_t)batch * sA;
#pragma unroll
        for (int s = 0; s < 2; ++s) {
            int idx = s * 256 + tid;
            int row = idx >> 2, cg = idx & 3;
            a16[s] = Ab + (size_t)(m0 + row) * K + k0 + 8 * bswz(row, cg);
        }
    }

    f32x4 acc[4][NFRAG] = {};
    const int nk = kLen / BK;
    for (int kt = 0; kt < nk; ++kt) {
        if constexpr (A_F32) {
            float* lAf = (float*)lA;
#pragma unroll
            for (int s = 0; s < 4; ++s) { g2lds16(a32[s], &lAf[(s * 256 + tid) * 4]); a32[s] += BK; }
        } else {
#pragma unroll
            for (int s = 0; s < 2; ++s) { g2lds16(a16[s], &lA[(s * 256 + tid) * 8]); a16[s] += BK; }
        }
#pragma unroll
        for (int s = 0; s < BSH; ++s) { g2lds16(bp[s], &lB[(s * 256 + tid) * 8]); bp[s] += BK; }
        __syncthreads();

        short8 af[4], bfr[NFRAG];
#pragma unroll
        for (int i = 0; i < 4; ++i) {
            const int rA = wr * 64 + i * 16 + ml;
            if constexpr (A_F32) {
                const float* lAf = (const float*)lA;
                float4 x0 = *(const float4*)&lAf[rA * 32 + 4 * fswz(rA, 2 * q)];
                float4 x1 = *(const float4*)&lAf[rA * 32 + 4 * fswz(rA, 2 * q + 1)];
                af[i][0] = f2bs(x0.x); af[i][1] = f2bs(x0.y);
                af[i][2] = f2bs(x0.z); af[i][3] = f2bs(x0.w);
                af[i][4] = f2bs(x1.x); af[i][5] = f2bs(x1.y);
                af[i][6] = f2bs(x1.z); af[i][7] = f2bs(x1.w);
            } else {
                af[i] = *(const short8*)&lA[rA * 32 + 8 * bswz(rA, q)];
            }
        }
#pragma unroll
        for (int j = 0; j < NFRAG; ++j) {
            const int rB = wc * (16 * NFRAG) + j * 16 + ml;
            bfr[j] = *(const short8*)&lB[rB * 32 + 8 * bswz(rB, q)];
        }
#pragma unroll
        for (int mi = 0; mi < 4; ++mi)
#pragma unroll
            for (int nj = 0; nj < NFRAG; ++nj)
                acc[mi][nj] = __builtin_amdgcn_mfma_f32_16x16x32_bf16(
                    af[mi], bfr[nj], acc[mi][nj], 0, 0, 0);
        __syncthreads();
    }

#pragma unroll
    for (int mi = 0; mi < 4; ++mi)
#pragma unroll
        for (int nj = 0; nj < NFRAG; ++nj)
#pragma unroll
            for (int r = 0; r < 4; ++r) {
                int row = m0 + wr * 64 + mi * 16 + q * 4 + r;
                int col = n0 + wc * (16 * NFRAG) + nj * 16 + ml;
                if constexpr (MODE == 1) {
                    float* Cf = (float*)Cv + (size_t)batch * sC;
                    atomicAdd(&Cf[(size_t)row * N + col], acc[mi][nj][r]);
                } else if constexpr (MODE == 0) {
                    ushort* Cb = (ushort*)Cv + (size_t)batch * sC;
                    Cb[(size_t)row * N + col] = (ushort)f2bs(acc[mi][nj][r]);
                } else if constexpr (MODE == 3) {
                    ushort* Cb = (ushort*)Cv + (size_t)batch * sC;
                    int plane = (row & 15) + 16 * ((col >> 3) & 3);
                    size_t pidx = (((size_t)(row >> 4) * (N >> 5) + (col >> 5)) * 64 + plane) * 8 + (col & 7);
                    Cb[pidx] = (ushort)f2bs(acc[mi][nj][r]);
                } else {
                    float* Cf = (float*)Cv + (size_t)batch * sC;
                    Cf[(size_t)row * N + col] = acc[mi][nj][r];
                }
            }
}

// ---- barrier-free wave GEMM on PACKED operands, register ping-pong ----
// Round-10 change: explicit depth-2 software pipeline. Fragments for iters
// k+2/k+3 load into the ping/pong sets while MFMAs for k/k+1 issue; the
// compiler emits fine-grained vmcnt(N) waits (no barrier anywhere).
template <int MODE, int MFRAG, int NFRAG>
__global__ __launch_bounds__(64, 2)
void gemm_wp(const ushort* __restrict__ Ap, const ushort* __restrict__ Bp,
             void* __restrict__ Cv, int N, int K, int kChunks,
             long sA, long sB, long sC)
{
    const int z      = blockIdx.z;
    const int batch  = z / kChunks;
    const int chunk  = z - batch * kChunks;
    const int ktiles = K >> 5;
    const int nkt    = ktiles / kChunks;   // must be even, >= 4
    const int kt0    = chunk * nkt;
    const int m0     = blockIdx.y * (MFRAG * 16);
    const int n0     = blockIdx.x * (NFRAG * 16);
    const int lane   = threadIdx.x;

    const ushort* Ab = Ap + (size_t)batch * sA;
    const ushort* Bb = Bp + (size_t)batch * sB;
    const ushort* ap[MFRAG];
    const ushort* bp[NFRAG];
#pragma unroll
    for (int f = 0; f < MFRAG; ++f)
        ap[f] = Ab + (((size_t)((m0 >> 4) + f) * ktiles + kt0) * 64 + lane) * 8;
#pragma unroll
    for (int f = 0; f < NFRAG; ++f)
        bp[f] = Bb + (((size_t)((n0 >> 4) + f) * ktiles + kt0) * 64 + lane) * 8;

    f32x4 acc[MFRAG][NFRAG] = {};
    short8 a0[MFRAG], b0[NFRAG], a1[MFRAG], b1[NFRAG];

    auto load = [&](short8* af, short8* bf) {
#pragma unroll
        for (int f = 0; f < MFRAG; ++f) { af[f] = *(const short8*)ap[f]; ap[f] += 512; }
#pragma unroll
        for (int f = 0; f < NFRAG; ++f) { bf[f] = *(const short8*)bp[f]; bp[f] += 512; }
    };
    auto mfma = [&](short8* af, short8* bf) {
#pragma unroll
        for (int mi = 0; mi < MFRAG; ++mi)
#pragma unroll
            for (int nj = 0; nj < NFRAG; ++nj)
                acc[mi][nj] = __builtin_amdgcn_mfma_f32_16x16x32_bf16(
                    af[mi], bf[nj], acc[mi][nj], 0, 0, 0);
    };

    load(a0, b0);            // kt 0
    load(a1, b1);            // kt 1
    for (int kt = 0; kt + 2 < nkt; kt += 2) {
        mfma(a0, b0);
        load(a0, b0);        // kt+2 (in flight across next mfma)
        mfma(a1, b1);
        load(a1, b1);        // kt+3
    }
    mfma(a0, b0);
    mfma(a1, b1);

    const int ml = lane & 15, q = lane >> 4;
#pragma unroll
    for (int mi = 0; mi < MFRAG; ++mi)
#pragma unroll
        for (int nj = 0; nj < NFRAG; ++nj)
#pragma unroll
            for (int r = 0; r < 4; ++r) {
                int row = m0 + mi * 16 + q * 4 + r;
                int col = n0 + nj * 16 + ml;
                if constexpr (MODE == 1) {
                    float* Cf = (float*)Cv + (size_t)batch * sC;
                    atomicAdd(&Cf[(size_t)row * N + col], acc[mi][nj][r]);
                } else {
                    float* Cf = (float*)Cv + (size_t)batch * sC;
                    Cf[(size_t)row * N + col] = acc[mi][nj][r];
                }
            }
}

// ---------------------------------------------------------------
// fp32 I/O.  O = X * (W^T (X^T X))   [associative]
//   G  = Xt * Xt^T   (packed wave-GEMM + reg pipeline, split-K=4, atomic)
//   Mt = Gf * Wt^T   (LDS gemm, A fp32 cvt fused; packed-bf16 store)
//   O  = Xb * Mt^T   (packed wave-GEMM + reg pipeline, fp32 store)
// d_out scratch: Xt packed @0 (16M) | Gf f32 @16M (8M) | Wt @28M (2M)
// ws: Xb packed 16M + Mt packed 4M  (requires ws >= 20M; fallback path else)
// ---------------------------------------------------------------
extern "C" void kernel_launch(void* const* d_in, const int* in_sizes, int n_in,
                              void* d_out, int out_size, void* d_ws, size_t ws_size,
                              hipStream_t stream)
{
    const int B = 2, N = 4096, D = 1024;
    const float* X = (const float*)d_in[0];
    const float* W = (const float*)d_in[1];
    float* out = (float*)d_out;

    char* ob = (char*)d_out;
    char* ws = (char*)d_ws;
    ushort* Xt = (ushort*)ob;                  // packed [B] rows=D, K=N, 16 MiB
    float*  Gf = (float*)(ob + (16ll << 20));  // [B][D][D] fp32, 8 MiB
    ushort* Wt = (ushort*)(ob + (28ll << 20)); // [D][D] bf16 normal, 2 MiB

    const bool bigws = ws_size >= (20ull << 20);
    ushort* Xb = bigws ? (ushort*)ws : nullptr;              // packed rows=N, K=D
    ushort* Mt = (ushort*)(ws + (bigws ? (16ll << 20) : 0)); // packed (or normal) 4 MiB

    // 1) Xt = packed(bf16(X)^T); Xb = packed(bf16(X)) when ws allows
    transpose_cvt<<<dim3(D / 64, N / 64, B), 256, 0, stream>>>(
        X, Xt, Xb, N, D, (long)N * D, (long)D * N, (long)N * D, 1);
    // 2) Wt = bf16(W)^T (normal layout, consumed by LDS gemm)
    transpose_cvt<<<dim3(D / 64, D / 64, 1), 256, 0, stream>>>(
        W, Wt, nullptr, D, D, 0, 0, 0, 0);
    // 3) zero split-K accumulator
    (void)hipMemsetAsync(Gf, 0, (size_t)B * D * D * sizeof(float), stream);
    // 4) Gf += Xt * Xt^T  (M=N=D, K=4096 split 4; nkt=32; 2048 waves)
    gemm_wp<1, 4, 4><<<dim3(D / 64, D / 64, B * 4), 64, 0, stream>>>(
        Xt, Xt, Gf, D, N, 4, (long)D * N, (long)D * N, (long)D * D);
    // 6) Mt = bf16(Gf) * Wt^T  (LDS gemm, packed store when bigws)
    if (bigws) {
        gemm_bt<3, 1, 2><<<dim3(D / 64, D / BM, B), 256, 0, stream>>>(
            (const void*)Gf, (const bf16*)Wt, Mt, D, D, D, 1,
            (long)D * D, 0, (long)D * D);
        // 7) O = Xb * Mt^T  (M=4096, N=D, K=D; nkt=32; 2048 waves)
        gemm_wp<2, 4, 4><<<dim3(D / 64, N / 64, B), 64, 0, stream>>>(
            Xb, Mt, out, D, D, 1, (long)N * D, (long)D * D, (long)N * D);
    } else {
        gemm_bt<0, 1, 2><<<dim3(D / 64, D / BM, B), 256, 0, stream>>>(
            (const void*)Gf, (const bf16*)Wt, Mt, D, D, D, 1,
            (long)D * D, 0, (long)D * D);
        gemm_bt<2, 1, 2><<<dim3(D / 64, N / BM, B), 256, 0, stream>>>(
            (const void*)X, (const bf16*)Mt, out, N, D, D, 1,
            (long)N * D, (long)D * D, (long)N * D);
    }
}